// Round 1
// baseline (112.034 us; speedup 1.0000x reference)
//
#include <hip/hip_runtime.h>

#define S_LEN 1024
#define D_DIM 128
#define NH    32
#define NKV   8
#define NB    2

typedef __bf16 bf16x8 __attribute__((ext_vector_type(8)));
typedef float  f32x4  __attribute__((ext_vector_type(4)));
typedef unsigned short u16x8 __attribute__((ext_vector_type(8)));

__device__ __forceinline__ unsigned short f2bf(float f) {
    unsigned int u = __float_as_uint(f);
    u += 0x7fffu + ((u >> 16) & 1u);      // RNE
    return (unsigned short)(u >> 16);
}

__device__ __forceinline__ float bf2f(unsigned short u) {
    return __uint_as_float(((unsigned int)u) << 16);
}

// ---------------- RoPE Q: q[B,S,H,D] f32 -> Qr[B,H,S,D] bf16 ----------------
__global__ __launch_bounds__(256) void rope_q_kernel(
    const float* __restrict__ q, const float* __restrict__ cosb,
    const float* __restrict__ sinb, unsigned short* __restrict__ Qr)
{
    int gid = blockIdx.x * 256 + threadIdx.x;
    int row = gid >> 6;            // (b*S + s)*NH + h
    int j   = gid & 63;
    int h  = row & (NH - 1);
    int bs = row >> 5;             // b*S + s
    int s  = bs & (S_LEN - 1);
    int b  = bs >> 10;
    const float* qp = q + (size_t)row * D_DIM;
    float x0 = qp[j];
    float x1 = qp[j + 64];
    float c  = cosb[s * D_DIM + j];
    float sn = sinb[s * D_DIM + j];
    size_t orow = ((size_t)(b * NH + h) * S_LEN + s) * D_DIM;
    Qr[orow + j]      = f2bf(x0 * c - x1 * sn);
    Qr[orow + j + 64] = f2bf(x1 * c + x0 * sn);
}

// ---------------- RoPE K: k[B,S,HKV,D] f32 -> Kr[B,HKV,S,D] bf16 ------------
__global__ __launch_bounds__(256) void rope_k_kernel(
    const float* __restrict__ k, const float* __restrict__ cosb,
    const float* __restrict__ sinb, unsigned short* __restrict__ Kr)
{
    int gid = blockIdx.x * 256 + threadIdx.x;
    int row = gid >> 6;            // (b*S + s)*NKV + hk
    int j   = gid & 63;
    int hk = row & (NKV - 1);
    int bs = row >> 3;
    int s  = bs & (S_LEN - 1);
    int b  = bs >> 10;
    const float* kp = k + (size_t)row * D_DIM;
    float x0 = kp[j];
    float x1 = kp[j + 64];
    float c  = cosb[s * D_DIM + j];
    float sn = sinb[s * D_DIM + j];
    size_t orow = ((size_t)(b * NKV + hk) * S_LEN + s) * D_DIM;
    Kr[orow + j]      = f2bf(x0 * c - x1 * sn);
    Kr[orow + j + 64] = f2bf(x1 * c + x0 * sn);
}

// -------- V transpose: v[B,S,HKV,D] f32 -> Vt[B,HKV,D,S] bf16 ---------------
__global__ __launch_bounds__(256) void transpose_v_kernel(
    const float* __restrict__ v, unsigned short* __restrict__ Vt)
{
    int blk   = blockIdx.x;            // (b, hk, stile)
    int stile = blk & 15;
    int hk    = (blk >> 4) & (NKV - 1);
    int b     = blk >> 7;
    int tid   = threadIdx.x;
    __shared__ unsigned short tile[64][132];   // [s][d], padded vs bank conflicts
#pragma unroll
    for (int i = 0; i < 8; i++) {
        int e    = i * 256 + tid;
        int srow = e >> 5;             // 0..63
        int dq   = (e & 31) * 4;
        const float* vp = v + (((size_t)(b * S_LEN + stile * 64 + srow) * NKV + hk) * D_DIM + dq);
        float4 val = *(const float4*)vp;
        tile[srow][dq + 0] = f2bf(val.x);
        tile[srow][dq + 1] = f2bf(val.y);
        tile[srow][dq + 2] = f2bf(val.z);
        tile[srow][dq + 3] = f2bf(val.w);
    }
    __syncthreads();
    size_t head = (size_t)(b * NKV + hk) * D_DIM * S_LEN;
#pragma unroll
    for (int i = 0; i < 4; i++) {
        int g  = i * 256 + tid;
        int d  = g >> 3;               // 0..127
        int c8 = g & 7;
        int s0 = c8 * 8;
        u16x8 pk;
#pragma unroll
        for (int jj = 0; jj < 8; jj++) pk[jj] = tile[s0 + jj][d];
        *(u16x8*)(Vt + head + (size_t)d * S_LEN + stile * 64 + s0) = pk;
    }
}

// ---------------- fused causal GQA flash attention --------------------------
// block = 256 thr = 4 waves; one block per (qt, h, b); QBLK=KVBLK=64
__global__ __launch_bounds__(256) void attn_kernel(
    const unsigned short* __restrict__ Qr,
    const unsigned short* __restrict__ Kr,
    const unsigned short* __restrict__ Vt,
    const float* __restrict__ scale_ptr,
    float* __restrict__ out)
{
    const int qt   = blockIdx.x;       // 0..15
    const int h    = blockIdx.y;       // 0..31
    const int b    = blockIdx.z;       // 0..1
    const int hk   = h >> 2;           // GQA: 4 q-heads per kv head
    const int tid  = threadIdx.x;
    const int w    = tid >> 6;
    const int lane = tid & 63;
    const int lr   = lane & 15;
    const int lg   = lane >> 4;

    const float sc = *scale_ptr;

    __shared__ unsigned short Kt[64 * 128];    // swizzled K tile
    __shared__ unsigned short Vs[128 * 64];    // swizzled V^T tile
    __shared__ unsigned short Pb[4][16 * 72];  // per-wave P, padded stride 72

    // Q fragments (registers, reused across all kv tiles)
    const unsigned short* qbase =
        Qr + ((size_t)(b * NH + h) * S_LEN + qt * 64 + w * 16 + lr) * D_DIM;
    bf16x8 qf[4];
#pragma unroll
    for (int kk = 0; kk < 4; kk++)
        qf[kk] = *(const bf16x8*)(qbase + lg * 8 + kk * 32);

    f32x4 o[8];                       // O accum: 8 d-tiles, rows lg*4+r
#pragma unroll
    for (int dt = 0; dt < 8; dt++) o[dt] = f32x4{0.f, 0.f, 0.f, 0.f};
    float m[4], lsum[4];
#pragma unroll
    for (int r = 0; r < 4; r++) { m[r] = -1e30f; lsum[r] = 0.f; }

    const unsigned short* khead = Kr + (size_t)(b * NKV + hk) * S_LEN * D_DIM;
    const unsigned short* vhead = Vt + (size_t)(b * NKV + hk) * D_DIM * S_LEN;

    for (int u = 0; u <= qt; ++u) {
        __syncthreads();                       // prev compute done before overwrite
        // ---- stage K tile [64][128] with XOR swizzle (16B chunks) ----
        {
            const unsigned short* kt = khead + (size_t)(u * 64) * D_DIM;
#pragma unroll
            for (int i = 0; i < 4; i++) {
                int e   = i * 256 + tid;       // chunk 0..1023
                int row = e >> 4;
                int cc  = e & 15;
                u16x8 val = *(const u16x8*)(kt + row * D_DIM + cc * 8);
                int cs = cc ^ (row & 7);
                *(u16x8*)(&Kt[row * 128 + cs * 8]) = val;
            }
            // ---- stage V^T tile [128][64] with XOR swizzle ----
            const unsigned short* vt = vhead + u * 64;
#pragma unroll
            for (int i = 0; i < 4; i++) {
                int e  = i * 256 + tid;        // chunk 0..1023
                int d  = e >> 3;
                int cc = e & 7;
                u16x8 val = *(const u16x8*)(vt + (size_t)d * S_LEN + cc * 8);
                int cs = cc ^ (d & 7);
                *(u16x8*)(&Vs[d * 64 + cs * 8]) = val;
            }
        }
        __syncthreads();                       // staging visible

        // ---- S = Q K^T : 4 col-tiles x 4 K-chunks ----
        f32x4 st[4];
#pragma unroll
        for (int kj = 0; kj < 4; kj++) st[kj] = f32x4{0.f, 0.f, 0.f, 0.f};
#pragma unroll
        for (int kj = 0; kj < 4; kj++) {
            int row = kj * 16 + lr;
#pragma unroll
            for (int kk = 0; kk < 4; kk++) {
                int cc = lg + kk * 4;
                int cs = cc ^ (row & 7);
                bf16x8 kf = *(const bf16x8*)(&Kt[row * 128 + cs * 8]);
                st[kj] = __builtin_amdgcn_mfma_f32_16x16x32_bf16(qf[kk], kf, st[kj], 0, 0, 0);
            }
        }
        // scale + causal mask (diagonal tile only)
#pragma unroll
        for (int kj = 0; kj < 4; kj++)
#pragma unroll
            for (int r = 0; r < 4; r++) st[kj][r] *= sc;
        if (u == qt) {
            int qrow = w * 16 + lg * 4;
#pragma unroll
            for (int kj = 0; kj < 4; kj++) {
                int col = kj * 16 + lr;
#pragma unroll
                for (int r = 0; r < 4; r++)
                    if (col > qrow + r) st[kj][r] = -1e30f;
            }
        }
        // ---- online softmax (rows = lg*4+r; 16-lane xor-shuffle reduce) ----
        float pm[4];
#pragma unroll
        for (int r = 0; r < 4; r++) {
            float mx = fmaxf(fmaxf(st[0][r], st[1][r]), fmaxf(st[2][r], st[3][r]));
            mx = fmaxf(mx, __shfl_xor(mx, 1));
            mx = fmaxf(mx, __shfl_xor(mx, 2));
            mx = fmaxf(mx, __shfl_xor(mx, 4));
            mx = fmaxf(mx, __shfl_xor(mx, 8));
            pm[r] = mx;
        }
        float pscale[4];
#pragma unroll
        for (int r = 0; r < 4; r++) {
            float mnew = fmaxf(m[r], pm[r]);
            pscale[r]  = __expf(m[r] - mnew);
            m[r] = mnew;
        }
        float rsum[4] = {0.f, 0.f, 0.f, 0.f};
#pragma unroll
        for (int kj = 0; kj < 4; kj++)
#pragma unroll
            for (int r = 0; r < 4; r++) {
                float p = __expf(st[kj][r] - m[r]);
                st[kj][r] = p;
                rsum[r] += p;
            }
#pragma unroll
        for (int r = 0; r < 4; r++) {
            float s4 = rsum[r];
            s4 += __shfl_xor(s4, 1);
            s4 += __shfl_xor(s4, 2);
            s4 += __shfl_xor(s4, 4);
            s4 += __shfl_xor(s4, 8);
            lsum[r] = lsum[r] * pscale[r] + s4;
#pragma unroll
            for (int dt = 0; dt < 8; dt++) o[dt][r] *= pscale[r];
        }
        // ---- P -> LDS (bf16), re-layout to A-fragments ----
        unsigned short* pbw = &Pb[w][0];
#pragma unroll
        for (int kj = 0; kj < 4; kj++)
#pragma unroll
            for (int r = 0; r < 4; r++)
                pbw[(lg * 4 + r) * 72 + kj * 16 + lr] = f2bf(st[kj][r]);
        __syncthreads();                       // orders P write -> P read
        // ---- O += P V ----
#pragma unroll
        for (int kk2 = 0; kk2 < 2; kk2++) {
            bf16x8 pf = *(const bf16x8*)(&pbw[lr * 72 + lg * 8 + kk2 * 32]);
#pragma unroll
            for (int dt = 0; dt < 8; dt++) {
                int vrow = dt * 16 + lr;
                int cc = lg + kk2 * 4;
                int cs = cc ^ (vrow & 7);
                bf16x8 vf = *(const bf16x8*)(&Vs[vrow * 64 + cs * 8]);
                o[dt] = __builtin_amdgcn_mfma_f32_16x16x32_bf16(pf, vf, o[dt], 0, 0, 0);
            }
        }
    }

    // ---- epilogue: divide by l, store f32 [B,S,H,D] ----
    float inv[4];
#pragma unroll
    for (int r = 0; r < 4; r++) inv[r] = 1.0f / lsum[r];
    float* obase = out + ((size_t)(b * S_LEN + qt * 64 + w * 16) * NH + h) * D_DIM;
#pragma unroll
    for (int dt = 0; dt < 8; dt++)
#pragma unroll
        for (int r = 0; r < 4; r++)
            obase[(size_t)(lg * 4 + r) * NH * D_DIM + dt * 16 + lr] = o[dt][r] * inv[r];
}

extern "C" void kernel_launch(void* const* d_in, const int* in_sizes, int n_in,
                              void* d_out, int out_size, void* d_ws, size_t ws_size,
                              hipStream_t stream) {
    const float* q    = (const float*)d_in[0];
    const float* k    = (const float*)d_in[1];
    const float* v    = (const float*)d_in[2];
    const float* cosb = (const float*)d_in[3];
    const float* sinb = (const float*)d_in[4];
    // d_in[5] = attention_mask: exactly causal -> implemented analytically
    const float* scale = (const float*)d_in[6];
    float* out = (float*)d_out;

    unsigned short* Qr = (unsigned short*)d_ws;
    unsigned short* Kr = Qr + (size_t)NB * NH  * S_LEN * D_DIM;
    unsigned short* Vt = Kr + (size_t)NB * NKV * S_LEN * D_DIM;

    rope_q_kernel<<<NB * S_LEN * NH / 4, 256, 0, stream>>>(q, cosb, sinb, Qr);
    rope_k_kernel<<<NB * S_LEN * NKV / 4, 256, 0, stream>>>(k, cosb, sinb, Kr);
    transpose_v_kernel<<<NB * NKV * (S_LEN / 64), 256, 0, stream>>>(v, Vt);
    dim3 grid(S_LEN / 64, NH, NB);
    attn_kernel<<<grid, 256, 0, stream>>>(Qr, Kr, Vt, scale, out);
}

// Round 2
// 74.510 us; speedup vs baseline: 1.5036x; 1.5036x over previous
//
#include <hip/hip_runtime.h>

#define S_LEN 1024
#define D_DIM 128
#define NH    32
#define NKV   8
#define NB    2

typedef __bf16 bf16x8 __attribute__((ext_vector_type(8)));
typedef float  f32x4  __attribute__((ext_vector_type(4)));
typedef unsigned short u16x8 __attribute__((ext_vector_type(8)));

__device__ __forceinline__ unsigned short f2bf(float f) {
    unsigned int u = __float_as_uint(f);
    u += 0x7fffu + ((u >> 16) & 1u);      // RNE
    return (unsigned short)(u >> 16);
}

// ------- RoPE Q (scale folded in): q[B,S,H,D] f32 -> Qr[B,H,S,D] bf16 -------
__global__ __launch_bounds__(256) void rope_q_kernel(
    const float* __restrict__ q, const float* __restrict__ cosb,
    const float* __restrict__ sinb, const float* __restrict__ scale_ptr,
    unsigned short* __restrict__ Qr)
{
    const float sc = *scale_ptr;
    int gid = blockIdx.x * 256 + threadIdx.x;
    int row = gid >> 6;            // (b*S + s)*NH + h
    int j   = gid & 63;
    int h  = row & (NH - 1);
    int bs = row >> 5;             // b*S + s
    int s  = bs & (S_LEN - 1);
    int b  = bs >> 10;
    const float* qp = q + (size_t)row * D_DIM;
    float x0 = qp[j];
    float x1 = qp[j + 64];
    float c  = cosb[s * D_DIM + j];
    float sn = sinb[s * D_DIM + j];
    size_t orow = ((size_t)(b * NH + h) * S_LEN + s) * D_DIM;
    Qr[orow + j]      = f2bf((x0 * c - x1 * sn) * sc);
    Qr[orow + j + 64] = f2bf((x1 * c + x0 * sn) * sc);
}

// ---------------- RoPE K: k[B,S,HKV,D] f32 -> Kr[B,HKV,S,D] bf16 ------------
__global__ __launch_bounds__(256) void rope_k_kernel(
    const float* __restrict__ k, const float* __restrict__ cosb,
    const float* __restrict__ sinb, unsigned short* __restrict__ Kr)
{
    int gid = blockIdx.x * 256 + threadIdx.x;
    int row = gid >> 6;            // (b*S + s)*NKV + hk
    int j   = gid & 63;
    int hk = row & (NKV - 1);
    int bs = row >> 3;
    int s  = bs & (S_LEN - 1);
    int b  = bs >> 10;
    const float* kp = k + (size_t)row * D_DIM;
    float x0 = kp[j];
    float x1 = kp[j + 64];
    float c  = cosb[s * D_DIM + j];
    float sn = sinb[s * D_DIM + j];
    size_t orow = ((size_t)(b * NKV + hk) * S_LEN + s) * D_DIM;
    Kr[orow + j]      = f2bf(x0 * c - x1 * sn);
    Kr[orow + j + 64] = f2bf(x1 * c + x0 * sn);
}

// -------- V transpose: v[B,S,HKV,D] f32 -> Vt[B,HKV,D,S] bf16 ---------------
__global__ __launch_bounds__(256) void transpose_v_kernel(
    const float* __restrict__ v, unsigned short* __restrict__ Vt)
{
    int blk   = blockIdx.x;            // (b, hk, stile)
    int stile = blk & 15;
    int hk    = (blk >> 4) & (NKV - 1);
    int b     = blk >> 7;
    int tid   = threadIdx.x;
    __shared__ unsigned short tile[64][132];   // [s][d], padded vs bank conflicts
#pragma unroll
    for (int i = 0; i < 8; i++) {
        int e    = i * 256 + tid;
        int srow = e >> 5;             // 0..63
        int dq   = (e & 31) * 4;
        const float* vp = v + (((size_t)(b * S_LEN + stile * 64 + srow) * NKV + hk) * D_DIM + dq);
        float4 val = *(const float4*)vp;
        tile[srow][dq + 0] = f2bf(val.x);
        tile[srow][dq + 1] = f2bf(val.y);
        tile[srow][dq + 2] = f2bf(val.z);
        tile[srow][dq + 3] = f2bf(val.w);
    }
    __syncthreads();
    size_t head = (size_t)(b * NKV + hk) * D_DIM * S_LEN;
#pragma unroll
    for (int i = 0; i < 4; i++) {
        int g  = i * 256 + tid;
        int d  = g >> 3;               // 0..127
        int c8 = g & 7;
        int s0 = c8 * 8;
        u16x8 pk;
#pragma unroll
        for (int jj = 0; jj < 8; jj++) pk[jj] = tile[s0 + jj][d];
        *(u16x8*)(Vt + head + (size_t)d * S_LEN + stile * 64 + s0) = pk;
    }
}

// ---------------- fused causal GQA flash attention --------------------------
// block = 256 thr = 4 waves; one block per (q-tile PAIR p, h, b)
// pass 0: qt = 15-p, pass 1: qt = p  -> every block does exactly 17 kv-tiles.
__global__ __launch_bounds__(256) void attn_kernel(
    const unsigned short* __restrict__ Qr,
    const unsigned short* __restrict__ Kr,
    const unsigned short* __restrict__ Vt,
    float* __restrict__ out)
{
    const int p    = blockIdx.x;       // 0..7 (pair index)
    const int h    = blockIdx.y;       // 0..31
    const int b    = blockIdx.z;       // 0..1
    const int hk   = h >> 2;           // GQA: 4 q-heads per kv head
    const int tid  = threadIdx.x;
    const int w    = tid >> 6;
    const int lane = tid & 63;
    const int lr   = lane & 15;
    const int lg   = lane >> 4;

    __shared__ unsigned short Kt[64 * 128];    // swizzled K tile
    __shared__ unsigned short Vs[128 * 64];    // swizzled V^T tile
    __shared__ unsigned short Pb[4][16 * 72];  // per-wave P, padded stride 72

    const unsigned short* khead = Kr + (size_t)(b * NKV + hk) * S_LEN * D_DIM;
    const unsigned short* vhead = Vt + (size_t)(b * NKV + hk) * D_DIM * S_LEN;

    // per-thread constant staging geometry (i-th chunk at row +16i / +32i)
    const int krow0 = tid >> 4;                 // 0..15
    const int kcc   = tid & 15;
    const int kcs   = kcc ^ (krow0 & 7);
    const int vd0   = tid >> 3;                 // 0..31
    const int vcc   = tid & 7;
    const int vcs   = vcc ^ (vd0 & 7);

    u16x8 kreg[4], vreg[4];                     // in-flight next tile

    auto issue = [&](int u) {
        const unsigned short* kt = khead + (size_t)u * 64 * D_DIM;
        const unsigned short* vt = vhead + u * 64;
#pragma unroll
        for (int i = 0; i < 4; i++)
            kreg[i] = *(const u16x8*)(kt + (size_t)(krow0 + 16 * i) * D_DIM + kcc * 8);
#pragma unroll
        for (int i = 0; i < 4; i++)
            vreg[i] = *(const u16x8*)(vt + (size_t)(vd0 + 32 * i) * S_LEN + vcc * 8);
    };
    auto commit = [&]() {
#pragma unroll
        for (int i = 0; i < 4; i++)
            *(u16x8*)(&Kt[(krow0 + 16 * i) * 128 + kcs * 8]) = kreg[i];
#pragma unroll
        for (int i = 0; i < 4; i++)
            *(u16x8*)(&Vs[(vd0 + 32 * i) * 64 + vcs * 8]) = vreg[i];
    };

#pragma unroll 1
    for (int pass = 0; pass < 2; ++pass) {
        const int qt = (pass == 0) ? (15 - p) : p;

        // Q fragments (registers, reused across all kv tiles of this pass)
        const unsigned short* qbase =
            Qr + ((size_t)(b * NH + h) * S_LEN + qt * 64 + w * 16 + lr) * D_DIM;
        bf16x8 qf[4];
#pragma unroll
        for (int kk = 0; kk < 4; kk++)
            qf[kk] = *(const bf16x8*)(qbase + lg * 8 + kk * 32);

        f32x4 o[8];
#pragma unroll
        for (int dt = 0; dt < 8; dt++) o[dt] = f32x4{0.f, 0.f, 0.f, 0.f};
        float m[4], lsum[4];
#pragma unroll
        for (int r = 0; r < 4; r++) { m[r] = -1e30f; lsum[r] = 0.f; }

        issue(0);                              // prefetch tile 0

#pragma unroll 1
        for (int u = 0; u <= qt; ++u) {
            __syncthreads();                   // all waves done reading prev tile
            commit();                          // vmcnt drain handled by compiler
            __syncthreads();                   // staged tile visible
            if (u < qt) issue(u + 1);          // loads fly during compute

            // ---- S = Q K^T ----
            f32x4 st[4];
#pragma unroll
            for (int kj = 0; kj < 4; kj++) st[kj] = f32x4{0.f, 0.f, 0.f, 0.f};
#pragma unroll
            for (int kj = 0; kj < 4; kj++) {
                if (u < qt || kj <= w) {       // skip fully-masked diag sub-tiles
                    int row = kj * 16 + lr;
#pragma unroll
                    for (int kk = 0; kk < 4; kk++) {
                        int cc = lg + kk * 4;
                        int cs = cc ^ (row & 7);
                        bf16x8 kf = *(const bf16x8*)(&Kt[row * 128 + cs * 8]);
                        st[kj] = __builtin_amdgcn_mfma_f32_16x16x32_bf16(qf[kk], kf, st[kj], 0, 0, 0);
                    }
                }
            }
            if (u == qt) {                     // causal mask, diagonal tile
                int qrow = w * 16 + lg * 4;
#pragma unroll
                for (int kj = 0; kj < 4; kj++) {
                    int col = kj * 16 + lr;
#pragma unroll
                    for (int r = 0; r < 4; r++)
                        if (col > qrow + r) st[kj][r] = -1e30f;
                }
            }

            // ---- online softmax (rows = lg*4+r; 16-lane xor reduce) ----
            float pm[4];
#pragma unroll
            for (int r = 0; r < 4; r++) {
                float mx = fmaxf(fmaxf(st[0][r], st[1][r]), fmaxf(st[2][r], st[3][r]));
                mx = fmaxf(mx, __shfl_xor(mx, 1));
                mx = fmaxf(mx, __shfl_xor(mx, 2));
                mx = fmaxf(mx, __shfl_xor(mx, 4));
                mx = fmaxf(mx, __shfl_xor(mx, 8));
                pm[r] = mx;
            }
            // T13 defer-max: only rescale when some row grew by > 8
            bool grew = false;
#pragma unroll
            for (int r = 0; r < 4; r++) grew = grew || (pm[r] > m[r] + 8.f);
            if (__any(grew)) {
#pragma unroll
                for (int r = 0; r < 4; r++) {
                    float mnew = fmaxf(m[r], pm[r]);
                    float ps   = __expf(m[r] - mnew);
                    m[r] = mnew;
                    lsum[r] *= ps;
#pragma unroll
                    for (int dt = 0; dt < 8; dt++) o[dt][r] *= ps;
                }
            }
            float rsum[4] = {0.f, 0.f, 0.f, 0.f};
#pragma unroll
            for (int kj = 0; kj < 4; kj++)
#pragma unroll
                for (int r = 0; r < 4; r++) {
                    float pv = __expf(st[kj][r] - m[r]);
                    st[kj][r] = pv;
                    rsum[r] += pv;
                }
#pragma unroll
            for (int r = 0; r < 4; r++) {
                float s4 = rsum[r];
                s4 += __shfl_xor(s4, 1);
                s4 += __shfl_xor(s4, 2);
                s4 += __shfl_xor(s4, 4);
                s4 += __shfl_xor(s4, 8);
                lsum[r] += s4;
            }

            // ---- P -> per-wave LDS (intra-wave ordering only, no barrier) ----
            unsigned short* pbw = &Pb[w][0];
#pragma unroll
            for (int kj = 0; kj < 4; kj++)
#pragma unroll
                for (int r = 0; r < 4; r++)
                    pbw[(lg * 4 + r) * 72 + kj * 16 + lr] = f2bf(st[kj][r]);

            // ---- O += P V ----
#pragma unroll
            for (int kk2 = 0; kk2 < 2; kk2++) {
                bf16x8 pf = *(const bf16x8*)(&pbw[lr * 72 + lg * 8 + kk2 * 32]);
#pragma unroll
                for (int dt = 0; dt < 8; dt++) {
                    int vrow = dt * 16 + lr;
                    int cc = lg + kk2 * 4;
                    int cs = cc ^ (vrow & 7);
                    bf16x8 vf = *(const bf16x8*)(&Vs[vrow * 64 + cs * 8]);
                    o[dt] = __builtin_amdgcn_mfma_f32_16x16x32_bf16(pf, vf, o[dt], 0, 0, 0);
                }
            }
        }

        // ---- epilogue: divide by l, store f32 [B,S,H,D] ----
        float inv[4];
#pragma unroll
        for (int r = 0; r < 4; r++) inv[r] = 1.0f / lsum[r];
        float* obase = out + ((size_t)(b * S_LEN + qt * 64 + w * 16) * NH + h) * D_DIM;
#pragma unroll
        for (int dt = 0; dt < 8; dt++)
#pragma unroll
            for (int r = 0; r < 4; r++)
                obase[(size_t)(lg * 4 + r) * NH * D_DIM + dt * 16 + lr] = o[dt][r] * inv[r];
    }
}

extern "C" void kernel_launch(void* const* d_in, const int* in_sizes, int n_in,
                              void* d_out, int out_size, void* d_ws, size_t ws_size,
                              hipStream_t stream) {
    const float* q    = (const float*)d_in[0];
    const float* k    = (const float*)d_in[1];
    const float* v    = (const float*)d_in[2];
    const float* cosb = (const float*)d_in[3];
    const float* sinb = (const float*)d_in[4];
    // d_in[5] = attention_mask: exactly causal -> implemented analytically
    const float* scale = (const float*)d_in[6];
    float* out = (float*)d_out;

    unsigned short* Qr = (unsigned short*)d_ws;
    unsigned short* Kr = Qr + (size_t)NB * NH  * S_LEN * D_DIM;
    unsigned short* Vt = Kr + (size_t)NB * NKV * S_LEN * D_DIM;

    rope_q_kernel<<<NB * S_LEN * NH / 4, 256, 0, stream>>>(q, cosb, sinb, scale, Qr);
    rope_k_kernel<<<NB * S_LEN * NKV / 4, 256, 0, stream>>>(k, cosb, sinb, Kr);
    transpose_v_kernel<<<NB * NKV * (S_LEN / 64), 256, 0, stream>>>(v, Vt);
    dim3 grid(8, NH, NB);
    attn_kernel<<<grid, 256, 0, stream>>>(Qr, Kr, Vt, out);
}

// Round 3
// 66.260 us; speedup vs baseline: 1.6908x; 1.1245x over previous
//
#include <hip/hip_runtime.h>

#define S_LEN 1024
#define D_DIM 128
#define NH    32
#define NKV   8
#define NB    2

typedef __bf16 bf16x8 __attribute__((ext_vector_type(8)));
typedef float  f32x4  __attribute__((ext_vector_type(4)));
typedef unsigned short u16x8 __attribute__((ext_vector_type(8)));

__device__ __forceinline__ unsigned short f2bf(float f) {
    unsigned int u = __float_as_uint(f);
    u += 0x7fffu + ((u >> 16) & 1u);      // RNE
    return (unsigned short)(u >> 16);
}

// async global->LDS, 16B per lane; LDS dest is wave-uniform base + lane*16
__device__ __forceinline__ void gld_lds16(const unsigned short* g, unsigned short* l) {
    __builtin_amdgcn_global_load_lds(
        (const __attribute__((address_space(1))) unsigned int*)(g),
        (__attribute__((address_space(3))) unsigned int*)(l), 16, 0, 0);
}

// --- RoPE Q (scale*log2e folded): q[B,S,H,D] f32 -> Qr[B,H,S,D] bf16 --------
__global__ __launch_bounds__(256) void rope_q_kernel(
    const float* __restrict__ q, const float* __restrict__ cosb,
    const float* __restrict__ sinb, const float* __restrict__ scale_ptr,
    unsigned short* __restrict__ Qr)
{
    const float sc = *scale_ptr * 1.44269504088896f;   // log2(e): exp2 domain
    int gid = blockIdx.x * 256 + threadIdx.x;
    int row = gid >> 6;            // (b*S + s)*NH + h
    int j   = gid & 63;
    int h  = row & (NH - 1);
    int bs = row >> 5;             // b*S + s
    int s  = bs & (S_LEN - 1);
    int b  = bs >> 10;
    const float* qp = q + (size_t)row * D_DIM;
    float x0 = qp[j];
    float x1 = qp[j + 64];
    float c  = cosb[s * D_DIM + j];
    float sn = sinb[s * D_DIM + j];
    size_t orow = ((size_t)(b * NH + h) * S_LEN + s) * D_DIM;
    Qr[orow + j]      = f2bf((x0 * c - x1 * sn) * sc);
    Qr[orow + j + 64] = f2bf((x1 * c + x0 * sn) * sc);
}

// ---------------- RoPE K: k[B,S,HKV,D] f32 -> Kr[B,HKV,S,D] bf16 ------------
__global__ __launch_bounds__(256) void rope_k_kernel(
    const float* __restrict__ k, const float* __restrict__ cosb,
    const float* __restrict__ sinb, unsigned short* __restrict__ Kr)
{
    int gid = blockIdx.x * 256 + threadIdx.x;
    int row = gid >> 6;            // (b*S + s)*NKV + hk
    int j   = gid & 63;
    int hk = row & (NKV - 1);
    int bs = row >> 3;
    int s  = bs & (S_LEN - 1);
    int b  = bs >> 10;
    const float* kp = k + (size_t)row * D_DIM;
    float x0 = kp[j];
    float x1 = kp[j + 64];
    float c  = cosb[s * D_DIM + j];
    float sn = sinb[s * D_DIM + j];
    size_t orow = ((size_t)(b * NKV + hk) * S_LEN + s) * D_DIM;
    Kr[orow + j]      = f2bf(x0 * c - x1 * sn);
    Kr[orow + j + 64] = f2bf(x1 * c + x0 * sn);
}

// -------- V transpose: v[B,S,HKV,D] f32 -> Vt[B,HKV,D,S] bf16 ---------------
__global__ __launch_bounds__(256) void transpose_v_kernel(
    const float* __restrict__ v, unsigned short* __restrict__ Vt)
{
    int blk   = blockIdx.x;            // (b, hk, stile)
    int stile = blk & 15;
    int hk    = (blk >> 4) & (NKV - 1);
    int b     = blk >> 7;
    int tid   = threadIdx.x;
    __shared__ unsigned short tile[64][132];
#pragma unroll
    for (int i = 0; i < 8; i++) {
        int e    = i * 256 + tid;
        int srow = e >> 5;
        int dq   = (e & 31) * 4;
        const float* vp = v + (((size_t)(b * S_LEN + stile * 64 + srow) * NKV + hk) * D_DIM + dq);
        float4 val = *(const float4*)vp;
        tile[srow][dq + 0] = f2bf(val.x);
        tile[srow][dq + 1] = f2bf(val.y);
        tile[srow][dq + 2] = f2bf(val.z);
        tile[srow][dq + 3] = f2bf(val.w);
    }
    __syncthreads();
    size_t head = (size_t)(b * NKV + hk) * D_DIM * S_LEN;
#pragma unroll
    for (int i = 0; i < 4; i++) {
        int g  = i * 256 + tid;
        int d  = g >> 3;
        int c8 = g & 7;
        int s0 = c8 * 8;
        u16x8 pk;
#pragma unroll
        for (int jj = 0; jj < 8; jj++) pk[jj] = tile[s0 + jj][d];
        *(u16x8*)(Vt + head + (size_t)d * S_LEN + stile * 64 + s0) = pk;
    }
}

// ---------------- fused causal GQA flash attention --------------------------
// 4 waves/block, QBLK=64 (16 rows/wave), KVBLK=64, paired q-tiles (17 iters),
// double-buffered K/V staged via global_load_lds, 1 barrier per tile.
__global__ __launch_bounds__(256, 2) void attn_kernel(
    const unsigned short* __restrict__ Qr,
    const unsigned short* __restrict__ Kr,
    const unsigned short* __restrict__ Vt,
    float* __restrict__ out)
{
    const int p    = blockIdx.x;       // 0..7 (pair index)
    const int h    = blockIdx.y;       // 0..31
    const int b    = blockIdx.z;       // 0..1
    const int hk   = h >> 2;           // GQA
    const int tid  = threadIdx.x;
    const int w    = tid >> 6;
    const int lane = tid & 63;
    const int lr   = lane & 15;
    const int lg   = lane >> 4;

    __shared__ unsigned short Kt[2][64 * 128];   // dbuf, swizzled content
    __shared__ unsigned short Vs[2][128 * 64];   // dbuf, swizzled content
    __shared__ unsigned short Pb[4][16 * 64];    // per-wave P, 16B-chunk swizzle

    const unsigned short* khead = Kr + (size_t)(b * NKV + hk) * S_LEN * D_DIM;
    const unsigned short* vhead = Vt + (size_t)(b * NKV + hk) * D_DIM * S_LEN;

    // staging geometry: wave w stages K rows [16w,16w+16), V d-rows [32w,32w+32)
    // LDS dest linear; global src pre-swizzled (XOR is its own inverse).
    auto stage = [&](int u, int buf) {
        const unsigned short* kt = khead + (size_t)u * 64 * D_DIM;
#pragma unroll
        for (int n = 0; n < 4; n++) {
            int row = w * 16 + n * 4 + (lane >> 4);
            int cc  = (lane & 15) ^ (row & 7);
            gld_lds16(kt + (size_t)row * D_DIM + cc * 8,
                      &Kt[buf][(w * 16 + n * 4) * 128]);
        }
        const unsigned short* vt = vhead + u * 64;
#pragma unroll
        for (int n = 0; n < 4; n++) {
            int d  = w * 32 + n * 8 + (lane >> 3);
            int cc = (lane & 7) ^ (d & 7);
            gld_lds16(vt + (size_t)d * S_LEN + cc * 8,
                      &Vs[buf][(w * 32 + n * 8) * 64]);
        }
    };

#pragma unroll 1
    for (int pass = 0; pass < 2; ++pass) {
        const int qt = (pass == 0) ? (15 - p) : p;

        // Q fragments (registers, reused across all kv tiles of this pass)
        const unsigned short* qbase =
            Qr + ((size_t)(b * NH + h) * S_LEN + qt * 64 + w * 16 + lr) * D_DIM;
        bf16x8 qf[4];
#pragma unroll
        for (int kk = 0; kk < 4; kk++)
            qf[kk] = *(const bf16x8*)(qbase + lg * 8 + kk * 32);

        f32x4 o[8];                    // O: rows q = w*16 + lg*4+r, col d = dt*16+lr
#pragma unroll
        for (int dt = 0; dt < 8; dt++) o[dt] = f32x4{0.f, 0.f, 0.f, 0.f};
        float m_run = -1e30f, lsum = 0.f;   // softmax state for q-row w*16+lr

        if (pass) __syncthreads();     // protect buffers from prev pass readers
        stage(0, 0);

#pragma unroll 1
        for (int u = 0; u <= qt; ++u) {
            const int cur = u & 1;
            __syncthreads();           // drains vmcnt: stage(u) complete
            if (u < qt) stage(u + 1, cur ^ 1);   // flies during compute

            // ---- S^T = K Q^T : st[kj][r] = S[q = w*16+lr][k = kj*16+lg*4+r] ----
            f32x4 st[4];
#pragma unroll
            for (int kj = 0; kj < 4; kj++) st[kj] = f32x4{0.f, 0.f, 0.f, 0.f};
            __builtin_amdgcn_s_setprio(1);
#pragma unroll
            for (int kj = 0; kj < 4; kj++) {
                if (u < qt || kj <= w) {
                    int row = kj * 16 + lr;
#pragma unroll
                    for (int kk = 0; kk < 4; kk++) {
                        int cs = (lg + kk * 4) ^ (row & 7);
                        bf16x8 kf = *(const bf16x8*)(&Kt[cur][row * 128 + cs * 8]);
                        st[kj] = __builtin_amdgcn_mfma_f32_16x16x32_bf16(kf, qf[kk], st[kj], 0, 0, 0);
                    }
                }
            }
            __builtin_amdgcn_s_setprio(0);

            if (u == qt) {             // causal mask on diagonal tile
#pragma unroll
                for (int kj = 0; kj < 4; kj++)
#pragma unroll
                    for (int r = 0; r < 4; r++)
                        if (kj * 16 + lg * 4 + r > w * 16 + lr) st[kj][r] = -1e30f;
            }

            // ---- online softmax, q-row lane-local (log2 domain) ----
            float lmax = fmaxf(fmaxf(fmaxf(st[0][0], st[0][1]), fmaxf(st[0][2], st[0][3])),
                               fmaxf(fmaxf(st[1][0], st[1][1]), fmaxf(st[1][2], st[1][3])));
            lmax = fmaxf(lmax,
                   fmaxf(fmaxf(fmaxf(st[2][0], st[2][1]), fmaxf(st[2][2], st[2][3])),
                         fmaxf(fmaxf(st[3][0], st[3][1]), fmaxf(st[3][2], st[3][3]))));
            float pm = fmaxf(lmax, __shfl_xor(lmax, 16));
            pm = fmaxf(pm, __shfl_xor(pm, 32));

            if (__any(pm > m_run + 8.f)) {       // T13 defer-max
                float mnew = fmaxf(m_run, pm);
                float ps   = exp2f(m_run - mnew);
                m_run = mnew;
                lsum *= ps;
#pragma unroll
                for (int r = 0; r < 4; r++) {
                    float psr = __shfl(ps, lg * 4 + r);  // factor of O-row lg*4+r
#pragma unroll
                    for (int dt = 0; dt < 8; dt++) o[dt][r] *= psr;
                }
            }
            float lsloc = 0.f;
#pragma unroll
            for (int kj = 0; kj < 4; kj++)
#pragma unroll
                for (int r = 0; r < 4; r++) {
                    float pv = exp2f(st[kj][r] - m_run);
                    st[kj][r] = pv;
                    lsloc += pv;
                }
            float t = lsloc + __shfl_xor(lsloc, 16);
            t += __shfl_xor(t, 32);
            lsum += t;

            // ---- P -> per-wave LDS, packed b64, 16B-chunk XOR swizzle ----
            char* pw = (char*)&Pb[w][0];
#pragma unroll
            for (int kj = 0; kj < 4; kj++) {
                unsigned int w0 = (unsigned)f2bf(st[kj][0]) | ((unsigned)f2bf(st[kj][1]) << 16);
                unsigned int w1 = (unsigned)f2bf(st[kj][2]) | ((unsigned)f2bf(st[kj][3]) << 16);
                int C = (2 * kj + (lg >> 1)) ^ (lr & 7);
                *(uint2*)(pw + lr * 128 + C * 16 + (lg & 1) * 8) = uint2{w0, w1};
            }

            // ---- O += P V ----
            __builtin_amdgcn_s_setprio(1);
#pragma unroll
            for (int kk2 = 0; kk2 < 2; kk2++) {
                int Cp = (lg + 4 * kk2) ^ (lr & 7);
                bf16x8 pf = *(const bf16x8*)(pw + lr * 128 + Cp * 16);
#pragma unroll
                for (int dt = 0; dt < 8; dt++) {
                    int vrow = dt * 16 + lr;
                    int cs = (lg + kk2 * 4) ^ (vrow & 7);
                    bf16x8 vf = *(const bf16x8*)(&Vs[cur][vrow * 64 + cs * 8]);
                    o[dt] = __builtin_amdgcn_mfma_f32_16x16x32_bf16(pf, vf, o[dt], 0, 0, 0);
                }
            }
            __builtin_amdgcn_s_setprio(0);
        }

        // ---- epilogue: normalize, store f32 [B,S,H,D] ----
        float rcp = 1.0f / lsum;                 // for q-row w*16+lr
        float invr[4];
#pragma unroll
        for (int r = 0; r < 4; r++) invr[r] = __shfl(rcp, lg * 4 + r);
        float* obase = out + ((size_t)(b * S_LEN + qt * 64 + w * 16) * NH + h) * D_DIM;
#pragma unroll
        for (int dt = 0; dt < 8; dt++)
#pragma unroll
            for (int r = 0; r < 4; r++)
                obase[(size_t)(lg * 4 + r) * NH * D_DIM + dt * 16 + lr] = o[dt][r] * invr[r];
    }
}

extern "C" void kernel_launch(void* const* d_in, const int* in_sizes, int n_in,
                              void* d_out, int out_size, void* d_ws, size_t ws_size,
                              hipStream_t stream) {
    const float* q    = (const float*)d_in[0];
    const float* k    = (const float*)d_in[1];
    const float* v    = (const float*)d_in[2];
    const float* cosb = (const float*)d_in[3];
    const float* sinb = (const float*)d_in[4];
    // d_in[5] = attention_mask: exactly causal -> implemented analytically
    const float* scale = (const float*)d_in[6];
    float* out = (float*)d_out;

    unsigned short* Qr = (unsigned short*)d_ws;
    unsigned short* Kr = Qr + (size_t)NB * NH  * S_LEN * D_DIM;
    unsigned short* Vt = Kr + (size_t)NB * NKV * S_LEN * D_DIM;

    rope_q_kernel<<<NB * S_LEN * NH / 4, 256, 0, stream>>>(q, cosb, sinb, scale, Qr);
    rope_k_kernel<<<NB * S_LEN * NKV / 4, 256, 0, stream>>>(k, cosb, sinb, Kr);
    transpose_v_kernel<<<NB * NKV * (S_LEN / 64), 256, 0, stream>>>(v, Vt);
    dim3 grid(8, NH, NB);
    attn_kernel<<<grid, 256, 0, stream>>>(Qr, Kr, Vt, out);
}